// Round 2
// baseline (10220.778 us; speedup 1.0000x reference)
//
#include <hip/hip_runtime.h>
#include <hip/hip_fp16.h>

#define BB 16
#define NN 1024
#define DD 256

typedef _Float16 h8 __attribute__((ext_vector_type(8)));
typedef _Float16 hv4 __attribute__((ext_vector_type(4)));
typedef float f32x4 __attribute__((ext_vector_type(4)));

#if __has_builtin(__builtin_amdgcn_exp2f)
#define EXP2F(x) __builtin_amdgcn_exp2f(x)
#else
#define EXP2F(x) exp2f(x)
#endif
#if __has_builtin(__builtin_amdgcn_logf)
#define LOG2F(x) __builtin_amdgcn_logf(x)
#else
#define LOG2F(x) log2f(x)
#endif

// log2-domain: A2s = -100*log2e*relu(1-S) - CPOS2*|i-j|   (pos prior folded in, fp16)
constexpr float K_A2  = -144.26950408889634f;                 // -100*log2(e)
constexpr float CPOS2 = (float)(0.2 * 1.4426950408889634 / 1023.0);
constexpr float C1    = 0.06931471805599453f;                 // ln2/10 : C_content = -C1*A2content
constexpr float BASE2 = -10.0f;                               // log2(1/1024 + 1e-12)

__device__ __forceinline__ float waveReduceSum(float v) {
#pragma unroll
  for (int o = 32; o; o >>= 1) v += __shfl_xor(v, o);
  return v;
}

// ---------------- K1: normalize rows of X and Y -> fp16 ----------------
__global__ __launch_bounds__(256) void normalize_kernel(
    const float* __restrict__ X, const float* __restrict__ Y,
    _Float16* __restrict__ Xh, _Float16* __restrict__ Yh) {
  int wave = threadIdx.x >> 6;
  int lane = threadIdx.x & 63;
  int row = blockIdx.x * 4 + wave;           // 0 .. 2*BB*NN-1
  const float* src;
  _Float16* dst;
  if (row < BB * NN) { src = X + (size_t)row * DD; dst = Xh + (size_t)row * DD; }
  else { int r2 = row - BB * NN; src = Y + (size_t)r2 * DD; dst = Yh + (size_t)r2 * DD; }
  float4 v = *(const float4*)(src + lane * 4);
  float ss = v.x * v.x + v.y * v.y + v.z * v.z + v.w * v.w;
  ss = waveReduceSum(ss);
  float sc = 1.0f / fmaxf(sqrtf(ss), 1e-12f);
  hv4 hv;
  hv[0] = (_Float16)(v.x * sc); hv[1] = (_Float16)(v.y * sc);
  hv[2] = (_Float16)(v.z * sc); hv[3] = (_Float16)(v.w * sc);
  *(hv4*)(dst + lane * 4) = hv;
}

// ---------------- K2: S = Ah . Bh^T per batch, write A2s (content+pos, fp16) ----
__global__ __launch_bounds__(256) void gemm_a2_kernel(
    const _Float16* __restrict__ Ah, const _Float16* __restrict__ Bh,
    _Float16* __restrict__ Out) {
  const int b = blockIdx.z;
  const int I0 = blockIdx.y * 128;
  const int J0 = blockIdx.x * 128;
  const int lane = threadIdx.x & 63;
  const int wave = threadIdx.x >> 6;
  const int m = lane & 15, quad = lane >> 4;
  const _Float16* Abase = Ah + ((size_t)b * NN + I0 + wave * 32) * DD;
  const _Float16* Bbase = Bh + ((size_t)b * NN + J0) * DD;
  f32x4 acc[2][8] = {};
  for (int k0 = 0; k0 < DD; k0 += 32) {
    int koff = k0 + quad * 8;
    h8 a0 = *(const h8*)(Abase + (size_t)m * DD + koff);
    h8 a1 = *(const h8*)(Abase + (size_t)(m + 16) * DD + koff);
#pragma unroll
    for (int t = 0; t < 8; ++t) {
      h8 bf = *(const h8*)(Bbase + (size_t)(t * 16 + m) * DD + koff);
      acc[0][t] = __builtin_amdgcn_mfma_f32_16x16x32_f16(a0, bf, acc[0][t], 0, 0, 0);
      acc[1][t] = __builtin_amdgcn_mfma_f32_16x16x32_f16(a1, bf, acc[1][t], 0, 0, 0);
    }
  }
  _Float16* Ob = Out + ((size_t)b * NN + I0 + wave * 32) * NN + J0;
#pragma unroll
  for (int a = 0; a < 2; ++a)
#pragma unroll
    for (int t = 0; t < 8; ++t)
#pragma unroll
      for (int r = 0; r < 4; ++r) {
        int row = a * 16 + quad * 4 + r;
        int col = t * 16 + m;
        float s = acc[a][t][r];
        float ri = (float)(I0 + wave * 32 + row);
        float ci = (float)(J0 + col);
        Ob[(size_t)row * NN + col] =
            (_Float16)(K_A2 * fmaxf(1.0f - s, 0.0f) - CPOS2 * fabsf(ri - ci));
      }
}

// ---------------- Sinkhorn persistent kernel (rows in registers) ----------------
__device__ __forceinline__ void group_barrier(unsigned* ctr, unsigned target) {
  __syncthreads();
  if (threadIdx.x == 0) {
    __threadfence();
    __hip_atomic_fetch_add(ctr, 1u, __ATOMIC_RELEASE, __HIP_MEMORY_SCOPE_AGENT);
    while (__hip_atomic_load(ctr, __ATOMIC_ACQUIRE, __HIP_MEMORY_SCOPE_AGENT) < target) {
      __builtin_amdgcn_s_sleep(1);
    }
    __threadfence();
  }
  __syncthreads();
}

__device__ __forceinline__ void loadVec16(const float* __restrict__ v, int j0,
                                          float (&out)[16]) {
  float4 g0 = *(const float4*)(v + j0);
  float4 g1 = *(const float4*)(v + j0 + 4);
  float4 g2 = *(const float4*)(v + 512 + j0);
  float4 g3 = *(const float4*)(v + 512 + j0 + 4);
  out[0] = g0.x; out[1] = g0.y; out[2] = g0.z; out[3] = g0.w;
  out[4] = g1.x; out[5] = g1.y; out[6] = g1.z; out[7] = g1.w;
  out[8] = g2.x; out[9] = g2.y; out[10] = g2.z; out[11] = g2.w;
  out[12] = g3.x; out[13] = g3.y; out[14] = g3.z; out[15] = g3.w;
}

__device__ __forceinline__ float lseRow(const h8 (&rw)[2], const float (&gv)[16]) {
  float x[16];
#pragma unroll
  for (int k = 0; k < 8; ++k) {
    x[k]     = (float)rw[0][k] + gv[k];
    x[8 + k] = (float)rw[1][k] + gv[8 + k];
  }
  float m = x[0];
#pragma unroll
  for (int k = 1; k < 16; ++k) m = fmaxf(m, x[k]);
#pragma unroll
  for (int o = 32; o; o >>= 1) m = fmaxf(m, __shfl_xor(m, o));
  float s = 0.f;
#pragma unroll
  for (int k = 0; k < 16; ++k) s += EXP2F(x[k] - m);
  s = waveReduceSum(s);
  return BASE2 - (m + LOG2F(s));
}

// grid 1024 blocks x 256 thr: batch = bid&15, 64 blocks/batch, wave owns 4 rows of
// A2 and 4 rows of A2T held in VGPRs across all 100 half-iterations.
__global__ __launch_bounds__(256, 4) void sinkhorn_kernel(
    const _Float16* __restrict__ A2, const _Float16* __restrict__ A2T,
    float* __restrict__ F, float* __restrict__ G,
    float* __restrict__ rOut, float* __restrict__ cOut,
    float* __restrict__ LrowOut, unsigned* __restrict__ bar) {
  const int batch = blockIdx.x & 15;
  const int lane = threadIdx.x & 63;
  const int wv = (blockIdx.x >> 4) * 4 + (threadIdx.x >> 6);  // 0..255
  const int r0 = wv * 4;
  const int j0 = lane * 8;
  const _Float16* Pa = A2 + (size_t)batch * NN * NN;
  const _Float16* Pt = A2T + (size_t)batch * NN * NN;
  float* Fb = F + batch * NN;
  float* Gb = G + batch * NN;
  unsigned* ctr = bar + batch * 64;   // 256B-padded counters

  h8 ra[4][2], rt[4][2];
#pragma unroll
  for (int r = 0; r < 4; ++r) {
    const _Float16* rowA = Pa + (size_t)(r0 + r) * NN + j0;
    const _Float16* rowT = Pt + (size_t)(r0 + r) * NN + j0;
    ra[r][0] = *(const h8*)(rowA);
    ra[r][1] = *(const h8*)(rowA + 512);
    rt[r][0] = *(const h8*)(rowT);
    rt[r][1] = *(const h8*)(rowT + 512);
  }
  unsigned tgt = 0;
  for (int it = 0; it < 50; ++it) {
    {
      float gv[16];
      loadVec16(Gb, j0, gv);
#pragma unroll
      for (int r = 0; r < 4; ++r) {
        float res = lseRow(ra[r], gv);
        if (lane == 0) Fb[r0 + r] = res;
      }
    }
    tgt += 64; group_barrier(ctr, tgt);
    {
      float fv[16];
      loadVec16(Fb, j0, fv);
#pragma unroll
      for (int r = 0; r < 4; ++r) {
        float res = lseRow(rt[r], fv);
        if (lane == 0) Gb[r0 + r] = res;
      }
    }
    tgt += 64; group_barrier(ctr, tgt);
  }
  // Epilogue: r_i = sum_j T, c_j = sum_i T, Lrow_i = sum_j T*C_content
  float fv[16], gv[16];
  loadVec16(Fb, j0, fv);
  loadVec16(Gb, j0, gv);
#pragma unroll
  for (int r = 0; r < 4; ++r) {
    int i = r0 + r;
    float fi = Fb[i];
    float gi = Gb[i];
    float fr = (float)i;
    float sr = 0.f, sl = 0.f, sc = 0.f;
#pragma unroll
    for (int k = 0; k < 8; ++k) {
      float a2a = (float)ra[r][0][k];
      float a2b = (float)ra[r][1][k];
      float Ta = EXP2F(a2a + fi + gv[k]);
      float Tb = EXP2F(a2b + fi + gv[8 + k]);
      sr += Ta + Tb;
      float ca = a2a + CPOS2 * fabsf(fr - (float)(j0 + k));
      float cb = a2b + CPOS2 * fabsf(fr - (float)(512 + j0 + k));
      sl = fmaf(Ta, ca, sl);
      sl = fmaf(Tb, cb, sl);
      sc += EXP2F((float)rt[r][0][k] + gi + fv[k]);
      sc += EXP2F((float)rt[r][1][k] + gi + fv[8 + k]);
    }
    sr = waveReduceSum(sr);
    sl = waveReduceSum(sl);
    sc = waveReduceSum(sc);
    if (lane == 0) {
      rOut[batch * NN + i] = sr;
      cOut[batch * NN + i] = sc;
      LrowOut[batch * NN + i] = -C1 * sl;
    }
  }
}

// ---------------- K6: num = T @ Emb ; accumulate sum((Ref - num/denom)^2) ----------
__global__ __launch_bounds__(512) void bary_kernel(
    const _Float16* __restrict__ P, const float* __restrict__ rowv,
    const float* __restrict__ colv, const float* __restrict__ denom,
    const float* __restrict__ Emb, const float* __restrict__ Ref,
    float* __restrict__ baryAcc) {
  const int b = blockIdx.y;
  const int I0 = blockIdx.x * 64;
  const _Float16* Pb = P + (size_t)b * NN * NN;
  const float* rv = rowv + b * NN;
  const float* cvv = colv + b * NN;
  const float* dn = denom + b * NN;
  const float* Eb = Emb + (size_t)b * NN * DD;
  const float* Rb = Ref + (size_t)b * NN * DD;
  __shared__ float Tl[64 * 64];
  __shared__ float red[8];
  const int t = threadIdx.x;
  const int rg = t >> 8, d = t & 255;
  float acc[32];
#pragma unroll
  for (int k = 0; k < 32; ++k) acc[k] = 0.f;
  for (int ch = 0; ch < 16; ++ch) {
    __syncthreads();
    {
      int jj = t & 63;
      int jabs = ch * 64 + jj;
      float gvv = cvv[jabs];
      int ii0 = (t >> 6) * 8;
#pragma unroll
      for (int k = 0; k < 8; ++k) {
        int ii = ii0 + k;
        int iabs = I0 + ii;
        float a2f = (float)Pb[(size_t)iabs * NN + jabs];
        Tl[ii * 64 + jj] = EXP2F(a2f + rv[iabs] + gvv);
      }
    }
    __syncthreads();
    const float* Yc = Eb + (size_t)(ch * 64) * DD + d;
    for (int jg = 0; jg < 16; ++jg) {
      float y0 = Yc[(size_t)(jg * 4 + 0) * DD];
      float y1 = Yc[(size_t)(jg * 4 + 1) * DD];
      float y2 = Yc[(size_t)(jg * 4 + 2) * DD];
      float y3 = Yc[(size_t)(jg * 4 + 3) * DD];
#pragma unroll
      for (int ii = 0; ii < 32; ++ii) {
        const float4 tv = *(const float4*)&Tl[(rg * 32 + ii) * 64 + jg * 4];
        acc[ii] = fmaf(tv.x, y0, acc[ii]);
        acc[ii] = fmaf(tv.y, y1, acc[ii]);
        acc[ii] = fmaf(tv.z, y2, acc[ii]);
        acc[ii] = fmaf(tv.w, y3, acc[ii]);
      }
    }
  }
  float vs = 0.f;
#pragma unroll
  for (int ii = 0; ii < 32; ++ii) {
    int iabs = I0 + rg * 32 + ii;
    float val = Rb[(size_t)iabs * DD + d] - acc[ii] / (dn[iabs] + 1e-8f);
    vs = fmaf(val, val, vs);
  }
  vs = waveReduceSum(vs);
  int lane = t & 63, wave = t >> 6;
  if (lane == 0) red[wave] = vs;
  __syncthreads();
  if (t == 0) {
    float tot = 0.f;
    for (int w = 0; w < 8; ++w) tot += red[w];
    atomicAdd(baryAcc + b, tot);
  }
}

// ---------------- K7: partial global sums X*r, Y*c ----------------
__global__ __launch_bounds__(256) void xg_kernel(
    const float* __restrict__ X, const float* __restrict__ Y,
    const float* __restrict__ r, const float* __restrict__ c,
    float* __restrict__ xgp, float* __restrict__ ygp) {
  const int b = blockIdx.y, seg = blockIdx.x, d = threadIdx.x;
  float ax = 0.f, ay = 0.f;
  for (int ii = 0; ii < 256; ++ii) {
    int i = seg * 256 + ii;
    float rvv = r[b * NN + i];
    float cvv = c[b * NN + i];
    ax = fmaf(X[((size_t)b * NN + i) * DD + d], rvv, ax);
    ay = fmaf(Y[((size_t)b * NN + i) * DD + d], cvv, ay);
  }
  xgp[(size_t)(b * 4 + seg) * DD + d] = ax;
  ygp[(size_t)(b * 4 + seg) * DD + d] = ay;
}

// ---------------- K8: per-batch finalize ----------------
__global__ __launch_bounds__(256) void finalize_batch(
    const float* __restrict__ r, const float* __restrict__ c,
    const float* __restrict__ Lrow, const float* __restrict__ xgp,
    const float* __restrict__ ygp, const float* __restrict__ baryA,
    const float* __restrict__ baryB, float* __restrict__ lossArr) {
  const int b = blockIdx.x;
  const int t = threadIdx.x;
  __shared__ float sd[256];
  auto bsum = [&](float v) -> float {
    sd[t] = v; __syncthreads();
    for (int o = 128; o; o >>= 1) { if (t < o) sd[t] += sd[t + o]; __syncthreads(); }
    float res = sd[0]; __syncthreads();
    return res;
  };
  float vr = 0.f, vc = 0.f, vl = 0.f;
  for (int k = 0; k < 4; ++k) {
    int i = t + 256 * k;
    vr += r[b * NN + i];
    vc += c[b * NN + i];
    vl += Lrow[b * NN + i];
  }
  float sumR = bsum(vr);
  float sumC = bsum(vc);
  float Lmain = bsum(vl);
  float xg = (xgp[(size_t)(b * 4 + 0) * DD + t] + xgp[(size_t)(b * 4 + 1) * DD + t] +
              xgp[(size_t)(b * 4 + 2) * DD + t] + xgp[(size_t)(b * 4 + 3) * DD + t]) /
             (sumR + 1e-8f);
  float yg = (ygp[(size_t)(b * 4 + 0) * DD + t] + ygp[(size_t)(b * 4 + 1) * DD + t] +
              ygp[(size_t)(b * 4 + 2) * DD + t] + ygp[(size_t)(b * 4 + 3) * DD + t]) /
             (sumC + 1e-8f);
  float nx = bsum(xg * xg);
  float ny = bsum(yg * yg);
  float dt = bsum(xg * yg);
  if (t == 0) {
    float mx = fmaxf(sqrtf(nx), 1e-12f);
    float my = fmaxf(sqrtf(ny), 1e-12f);
    float cosv = dt / (mx * my);
    float lb = (baryA[b] + baryB[b]) * (1.0f / ((float)NN * (float)DD));
    lossArr[b] = Lmain + 0.5f * lb + 0.2f * (1.0f - cosv);
  }
}

__global__ void final_mean(const float* __restrict__ lossArr, float* __restrict__ out) {
  int t = threadIdx.x;
  float v = (t < BB) ? lossArr[t] : 0.f;
  v = waveReduceSum(v);
  if (t == 0) out[0] = v * (1.0f / BB);
}

// ---------------- launch ----------------
extern "C" void kernel_launch(void* const* d_in, const int* in_sizes, int n_in,
                              void* d_out, int out_size, void* d_ws, size_t ws_size,
                              hipStream_t stream) {
  const float* X = (const float*)d_in[0];
  const float* Y = (const float*)d_in[1];
  float* out = (float*)d_out;
  char* ws = (char*)d_ws;
  size_t off = 0;
  auto take = [&](size_t bytes) -> char* {
    char* p = ws + off;
    off = (off + bytes + 255) & ~(size_t)255;
    return p;
  };
  _Float16* Xh = (_Float16*)take((size_t)BB * NN * DD * 2);
  _Float16* Yh = (_Float16*)take((size_t)BB * NN * DD * 2);
  _Float16* A2 = (_Float16*)take((size_t)BB * NN * NN * 2);
  _Float16* A2T = (_Float16*)take((size_t)BB * NN * NN * 2);
  size_t zstart = off;
  float* F = (float*)take((size_t)BB * NN * 4);
  float* G = (float*)take((size_t)BB * NN * 4);
  unsigned* bar = (unsigned*)take(16 * 64 * 4);
  float* baryA = (float*)take(64);
  float* baryB = (float*)take(64);
  size_t zlen = off - zstart;
  float* r = (float*)take((size_t)BB * NN * 4);
  float* c = (float*)take((size_t)BB * NN * 4);
  float* Lrow = (float*)take((size_t)BB * NN * 4);
  float* xgp = (float*)take((size_t)BB * 4 * DD * 4);
  float* ygp = (float*)take((size_t)BB * 4 * DD * 4);
  float* lossArr = (float*)take(64);
  (void)in_sizes; (void)n_in; (void)out_size; (void)ws_size;

  hipMemsetAsync(ws + zstart, 0, zlen, stream);

  normalize_kernel<<<dim3(2 * BB * NN / 4), dim3(256), 0, stream>>>(X, Y, Xh, Yh);
  gemm_a2_kernel<<<dim3(NN / 128, NN / 128, BB), dim3(256), 0, stream>>>(Xh, Yh, A2);
  gemm_a2_kernel<<<dim3(NN / 128, NN / 128, BB), dim3(256), 0, stream>>>(Yh, Xh, A2T);
  sinkhorn_kernel<<<dim3(1024), dim3(256), 0, stream>>>(A2, A2T, F, G, r, c, Lrow, bar);
  bary_kernel<<<dim3(NN / 64, BB), dim3(512), 0, stream>>>(A2, F, G, r, Y, X, baryA);
  bary_kernel<<<dim3(NN / 64, BB), dim3(512), 0, stream>>>(A2T, G, F, c, X, Y, baryB);
  xg_kernel<<<dim3(4, BB), dim3(256), 0, stream>>>(X, Y, r, c, xgp, ygp);
  finalize_batch<<<dim3(BB), dim3(256), 0, stream>>>(r, c, Lrow, xgp, ygp, baryA, baryB, lossArr);
  final_mean<<<dim3(1), dim3(64), 0, stream>>>(lossArr, out);
}

// Round 3
// 2913.997 us; speedup vs baseline: 3.5075x; 3.5075x over previous
//
#include <hip/hip_runtime.h>
#include <hip/hip_fp16.h>

#define BB 16
#define NN 1024
#define DD 256

typedef _Float16 h8 __attribute__((ext_vector_type(8)));
typedef _Float16 hv4 __attribute__((ext_vector_type(4)));
typedef float f32x4 __attribute__((ext_vector_type(4)));

#if __has_builtin(__builtin_amdgcn_exp2f)
#define EXP2F(x) __builtin_amdgcn_exp2f(x)
#else
#define EXP2F(x) exp2f(x)
#endif
#if __has_builtin(__builtin_amdgcn_logf)
#define LOG2F(x) __builtin_amdgcn_logf(x)
#else
#define LOG2F(x) log2f(x)
#endif

// log2-domain: A2s = -100*log2e*relu(1-S) - CPOS2*|i-j|   (pos prior folded in, fp16)
constexpr float K_A2  = -144.26950408889634f;                 // -100*log2(e)
constexpr float CPOS2 = (float)(0.2 * 1.4426950408889634 / 1023.0);
constexpr float C1    = 0.06931471805599453f;                 // ln2/10 : C_content = -C1*A2content
constexpr float BASE2 = -10.0f;                               // log2(1/1024 + 1e-12)

__device__ __forceinline__ float waveReduceSum(float v) {
#pragma unroll
  for (int o = 32; o; o >>= 1) v += __shfl_xor(v, o);
  return v;
}

// Pinned 16-byte load: inline asm so the compiler CANNOT rematerialize (re-load)
// the value inside the sinkhorn loop. Waitcnt embedded -> result valid on return.
__device__ __forceinline__ h8 lda16(const _Float16* p) {
  f32x4 r;
  asm volatile("global_load_dwordx4 %0, %1, off\n\ts_waitcnt vmcnt(0)"
               : "=v"(r) : "v"(p) : "memory");
  return __builtin_bit_cast(h8, r);
}

// ---------------- K1: normalize rows of X and Y -> fp16 ----------------
__global__ __launch_bounds__(256) void normalize_kernel(
    const float* __restrict__ X, const float* __restrict__ Y,
    _Float16* __restrict__ Xh, _Float16* __restrict__ Yh) {
  int wave = threadIdx.x >> 6;
  int lane = threadIdx.x & 63;
  int row = blockIdx.x * 4 + wave;           // 0 .. 2*BB*NN-1
  const float* src;
  _Float16* dst;
  if (row < BB * NN) { src = X + (size_t)row * DD; dst = Xh + (size_t)row * DD; }
  else { int r2 = row - BB * NN; src = Y + (size_t)r2 * DD; dst = Yh + (size_t)r2 * DD; }
  float4 v = *(const float4*)(src + lane * 4);
  float ss = v.x * v.x + v.y * v.y + v.z * v.z + v.w * v.w;
  ss = waveReduceSum(ss);
  float sc = 1.0f / fmaxf(sqrtf(ss), 1e-12f);
  hv4 hv;
  hv[0] = (_Float16)(v.x * sc); hv[1] = (_Float16)(v.y * sc);
  hv[2] = (_Float16)(v.z * sc); hv[3] = (_Float16)(v.w * sc);
  *(hv4*)(dst + lane * 4) = hv;
}

// ---------------- K2: S = Ah . Bh^T per batch, write A2s (content+pos, fp16) ----
__global__ __launch_bounds__(256) void gemm_a2_kernel(
    const _Float16* __restrict__ Ah, const _Float16* __restrict__ Bh,
    _Float16* __restrict__ Out) {
  const int b = blockIdx.z;
  const int I0 = blockIdx.y * 128;
  const int J0 = blockIdx.x * 128;
  const int lane = threadIdx.x & 63;
  const int wave = threadIdx.x >> 6;
  const int m = lane & 15, quad = lane >> 4;
  const _Float16* Abase = Ah + ((size_t)b * NN + I0 + wave * 32) * DD;
  const _Float16* Bbase = Bh + ((size_t)b * NN + J0) * DD;
  f32x4 acc[2][8] = {};
  for (int k0 = 0; k0 < DD; k0 += 32) {
    int koff = k0 + quad * 8;
    h8 a0 = *(const h8*)(Abase + (size_t)m * DD + koff);
    h8 a1 = *(const h8*)(Abase + (size_t)(m + 16) * DD + koff);
#pragma unroll
    for (int t = 0; t < 8; ++t) {
      h8 bf = *(const h8*)(Bbase + (size_t)(t * 16 + m) * DD + koff);
      acc[0][t] = __builtin_amdgcn_mfma_f32_16x16x32_f16(a0, bf, acc[0][t], 0, 0, 0);
      acc[1][t] = __builtin_amdgcn_mfma_f32_16x16x32_f16(a1, bf, acc[1][t], 0, 0, 0);
    }
  }
  _Float16* Ob = Out + ((size_t)b * NN + I0 + wave * 32) * NN + J0;
#pragma unroll
  for (int a = 0; a < 2; ++a)
#pragma unroll
    for (int t = 0; t < 8; ++t)
#pragma unroll
      for (int r = 0; r < 4; ++r) {
        int row = a * 16 + quad * 4 + r;
        int col = t * 16 + m;
        float s = acc[a][t][r];
        float ri = (float)(I0 + wave * 32 + row);
        float ci = (float)(J0 + col);
        Ob[(size_t)row * NN + col] =
            (_Float16)(K_A2 * fmaxf(1.0f - s, 0.0f) - CPOS2 * fabsf(ri - ci));
      }
}

// ---------------- Sinkhorn persistent kernel (asm-pinned rows in registers) -------
// Barrier: 16 arrivals/batch on ctr line; last arriver release-stores epoch to a
// SEPARATE flag line; others poll read-only with relaxed agent loads + s_sleep.
__device__ __forceinline__ void group_barrier(unsigned* ctr, unsigned* flag,
                                              unsigned epoch) {
  __syncthreads();
  if (threadIdx.x == 0) {
    __threadfence();  // release my f/g stores
    unsigned old = __hip_atomic_fetch_add(ctr, 1u, __ATOMIC_ACQ_REL,
                                          __HIP_MEMORY_SCOPE_AGENT);
    if (old == 16u * epoch - 1u) {
      __hip_atomic_store(flag, epoch, __ATOMIC_RELEASE, __HIP_MEMORY_SCOPE_AGENT);
    } else {
      while (__hip_atomic_load(flag, __ATOMIC_RELAXED, __HIP_MEMORY_SCOPE_AGENT) <
             epoch) {
        __builtin_amdgcn_s_sleep(8);
      }
    }
    __threadfence();  // acquire others' f/g stores
  }
  __syncthreads();
}

__device__ __forceinline__ void loadVec16(const float* __restrict__ v, int j0,
                                          float (&out)[16]) {
  float4 g0 = *(const float4*)(v + j0);
  float4 g1 = *(const float4*)(v + j0 + 4);
  float4 g2 = *(const float4*)(v + 512 + j0);
  float4 g3 = *(const float4*)(v + 512 + j0 + 4);
  out[0] = g0.x; out[1] = g0.y; out[2] = g0.z; out[3] = g0.w;
  out[4] = g1.x; out[5] = g1.y; out[6] = g1.z; out[7] = g1.w;
  out[8] = g2.x; out[9] = g2.y; out[10] = g2.z; out[11] = g2.w;
  out[12] = g3.x; out[13] = g3.y; out[14] = g3.z; out[15] = g3.w;
}

__device__ __forceinline__ float lseRow(const h8 (&rw)[2], const float (&gv)[16]) {
  float x[16];
#pragma unroll
  for (int k = 0; k < 8; ++k) {
    x[k]     = (float)rw[0][k] + gv[k];
    x[8 + k] = (float)rw[1][k] + gv[8 + k];
  }
  float m = x[0];
#pragma unroll
  for (int k = 1; k < 16; ++k) m = fmaxf(m, x[k]);
#pragma unroll
  for (int o = 32; o; o >>= 1) m = fmaxf(m, __shfl_xor(m, o));
  float s = 0.f;
#pragma unroll
  for (int k = 0; k < 16; ++k) s += EXP2F(x[k] - m);
  s = waveReduceSum(s);
  return BASE2 - (m + LOG2F(s));
}

// grid 256 blocks x 512 thr: batch = bid&15, 16 blocks/batch (1 block/CU,
// guaranteed co-resident). Each wave owns 8 rows of A2 and 8 rows of A2T,
// pinned in VGPRs via inline-asm loads (128 VGPRs of data).
__global__ __launch_bounds__(512, 2) void sinkhorn_kernel(
    const _Float16* __restrict__ A2, const _Float16* __restrict__ A2T,
    float* __restrict__ F, float* __restrict__ G,
    float* __restrict__ rOut, float* __restrict__ cOut,
    float* __restrict__ LrowOut, unsigned* __restrict__ bar) {
  const int batch = blockIdx.x & 15;
  const int blkSub = blockIdx.x >> 4;            // 0..15
  const int lane = threadIdx.x & 63;
  const int wave = threadIdx.x >> 6;             // 0..7
  const int r0 = blkSub * 64 + wave * 8;         // 8 rows per wave
  const int j0 = lane * 8;
  const _Float16* Pa = A2 + (size_t)batch * NN * NN;
  const _Float16* Pt = A2T + (size_t)batch * NN * NN;
  float* Fb = F + batch * NN;
  float* Gb = G + batch * NN;
  unsigned* ctr = bar + batch * 64;              // 256B stride per batch
  unsigned* flg = ctr + 32;                      // separate cacheline

  h8 ra[8][2], rt[8][2];
#pragma unroll
  for (int r = 0; r < 8; ++r) {
    const _Float16* rowA = Pa + (size_t)(r0 + r) * NN + j0;
    const _Float16* rowT = Pt + (size_t)(r0 + r) * NN + j0;
    ra[r][0] = lda16(rowA);
    ra[r][1] = lda16(rowA + 512);
    rt[r][0] = lda16(rowT);
    rt[r][1] = lda16(rowT + 512);
  }
  unsigned ep = 0;
  for (int it = 0; it < 50; ++it) {
    {
      float gv[16];
      loadVec16(Gb, j0, gv);
#pragma unroll
      for (int r = 0; r < 8; ++r) {
        float res = lseRow(ra[r], gv);
        if (lane == 0) Fb[r0 + r] = res;
      }
    }
    ++ep; group_barrier(ctr, flg, ep);
    {
      float fv[16];
      loadVec16(Fb, j0, fv);
#pragma unroll
      for (int r = 0; r < 8; ++r) {
        float res = lseRow(rt[r], fv);
        if (lane == 0) Gb[r0 + r] = res;
      }
    }
    ++ep; group_barrier(ctr, flg, ep);
  }
  // Epilogue: r_i = sum_j T, c_j = sum_i T, Lrow_i = sum_j T*C_content
  float fv[16], gv[16];
  loadVec16(Fb, j0, fv);
  loadVec16(Gb, j0, gv);
#pragma unroll
  for (int r = 0; r < 8; ++r) {
    int i = r0 + r;
    float fi = Fb[i];
    float gi = Gb[i];
    float fr = (float)i;
    float sr = 0.f, sl = 0.f, sc = 0.f;
#pragma unroll
    for (int k = 0; k < 8; ++k) {
      float a2a = (float)ra[r][0][k];
      float a2b = (float)ra[r][1][k];
      float Ta = EXP2F(a2a + fi + gv[k]);
      float Tb = EXP2F(a2b + fi + gv[8 + k]);
      sr += Ta + Tb;
      float ca = a2a + CPOS2 * fabsf(fr - (float)(j0 + k));
      float cb = a2b + CPOS2 * fabsf(fr - (float)(512 + j0 + k));
      sl = fmaf(Ta, ca, sl);
      sl = fmaf(Tb, cb, sl);
      sc += EXP2F((float)rt[r][0][k] + gi + fv[k]);
      sc += EXP2F((float)rt[r][1][k] + gi + fv[8 + k]);
    }
    sr = waveReduceSum(sr);
    sl = waveReduceSum(sl);
    sc = waveReduceSum(sc);
    if (lane == 0) {
      rOut[batch * NN + i] = sr;
      cOut[batch * NN + i] = sc;
      LrowOut[batch * NN + i] = -C1 * sl;
    }
  }
}

// ---------------- K6: num = T @ Emb ; accumulate sum((Ref - num/denom)^2) ----------
__global__ __launch_bounds__(512) void bary_kernel(
    const _Float16* __restrict__ P, const float* __restrict__ rowv,
    const float* __restrict__ colv, const float* __restrict__ denom,
    const float* __restrict__ Emb, const float* __restrict__ Ref,
    float* __restrict__ baryAcc) {
  const int b = blockIdx.y;
  const int I0 = blockIdx.x * 64;
  const _Float16* Pb = P + (size_t)b * NN * NN;
  const float* rv = rowv + b * NN;
  const float* cvv = colv + b * NN;
  const float* dn = denom + b * NN;
  const float* Eb = Emb + (size_t)b * NN * DD;
  const float* Rb = Ref + (size_t)b * NN * DD;
  __shared__ float Tl[64 * 64];
  __shared__ float red[8];
  const int t = threadIdx.x;
  const int rg = t >> 8, d = t & 255;
  float acc[32];
#pragma unroll
  for (int k = 0; k < 32; ++k) acc[k] = 0.f;
  for (int ch = 0; ch < 16; ++ch) {
    __syncthreads();
    {
      int jj = t & 63;
      int jabs = ch * 64 + jj;
      float gvv = cvv[jabs];
      int ii0 = (t >> 6) * 8;
#pragma unroll
      for (int k = 0; k < 8; ++k) {
        int ii = ii0 + k;
        int iabs = I0 + ii;
        float a2f = (float)Pb[(size_t)iabs * NN + jabs];
        Tl[ii * 64 + jj] = EXP2F(a2f + rv[iabs] + gvv);
      }
    }
    __syncthreads();
    const float* Yc = Eb + (size_t)(ch * 64) * DD + d;
    for (int jg = 0; jg < 16; ++jg) {
      float y0 = Yc[(size_t)(jg * 4 + 0) * DD];
      float y1 = Yc[(size_t)(jg * 4 + 1) * DD];
      float y2 = Yc[(size_t)(jg * 4 + 2) * DD];
      float y3 = Yc[(size_t)(jg * 4 + 3) * DD];
#pragma unroll
      for (int ii = 0; ii < 32; ++ii) {
        const float4 tv = *(const float4*)&Tl[(rg * 32 + ii) * 64 + jg * 4];
        acc[ii] = fmaf(tv.x, y0, acc[ii]);
        acc[ii] = fmaf(tv.y, y1, acc[ii]);
        acc[ii] = fmaf(tv.z, y2, acc[ii]);
        acc[ii] = fmaf(tv.w, y3, acc[ii]);
      }
    }
  }
  float vs = 0.f;
#pragma unroll
  for (int ii = 0; ii < 32; ++ii) {
    int iabs = I0 + rg * 32 + ii;
    float val = Rb[(size_t)iabs * DD + d] - acc[ii] / (dn[iabs] + 1e-8f);
    vs = fmaf(val, val, vs);
  }
  vs = waveReduceSum(vs);
  int lane = t & 63, wave = t >> 6;
  if (lane == 0) red[wave] = vs;
  __syncthreads();
  if (t == 0) {
    float tot = 0.f;
    for (int w = 0; w < 8; ++w) tot += red[w];
    atomicAdd(baryAcc + b, tot);
  }
}

// ---------------- K7: partial global sums X*r, Y*c ----------------
__global__ __launch_bounds__(256) void xg_kernel(
    const float* __restrict__ X, const float* __restrict__ Y,
    const float* __restrict__ r, const float* __restrict__ c,
    float* __restrict__ xgp, float* __restrict__ ygp) {
  const int b = blockIdx.y, seg = blockIdx.x, d = threadIdx.x;
  float ax = 0.f, ay = 0.f;
  for (int ii = 0; ii < 256; ++ii) {
    int i = seg * 256 + ii;
    float rvv = r[b * NN + i];
    float cvv = c[b * NN + i];
    ax = fmaf(X[((size_t)b * NN + i) * DD + d], rvv, ax);
    ay = fmaf(Y[((size_t)b * NN + i) * DD + d], cvv, ay);
  }
  xgp[(size_t)(b * 4 + seg) * DD + d] = ax;
  ygp[(size_t)(b * 4 + seg) * DD + d] = ay;
}

// ---------------- K8: per-batch finalize ----------------
__global__ __launch_bounds__(256) void finalize_batch(
    const float* __restrict__ r, const float* __restrict__ c,
    const float* __restrict__ Lrow, const float* __restrict__ xgp,
    const float* __restrict__ ygp, const float* __restrict__ baryA,
    const float* __restrict__ baryB, float* __restrict__ lossArr) {
  const int b = blockIdx.x;
  const int t = threadIdx.x;
  __shared__ float sd[256];
  auto bsum = [&](float v) -> float {
    sd[t] = v; __syncthreads();
    for (int o = 128; o; o >>= 1) { if (t < o) sd[t] += sd[t + o]; __syncthreads(); }
    float res = sd[0]; __syncthreads();
    return res;
  };
  float vr = 0.f, vc = 0.f, vl = 0.f;
  for (int k = 0; k < 4; ++k) {
    int i = t + 256 * k;
    vr += r[b * NN + i];
    vc += c[b * NN + i];
    vl += Lrow[b * NN + i];
  }
  float sumR = bsum(vr);
  float sumC = bsum(vc);
  float Lmain = bsum(vl);
  float xg = (xgp[(size_t)(b * 4 + 0) * DD + t] + xgp[(size_t)(b * 4 + 1) * DD + t] +
              xgp[(size_t)(b * 4 + 2) * DD + t] + xgp[(size_t)(b * 4 + 3) * DD + t]) /
             (sumR + 1e-8f);
  float yg = (ygp[(size_t)(b * 4 + 0) * DD + t] + ygp[(size_t)(b * 4 + 1) * DD + t] +
              ygp[(size_t)(b * 4 + 2) * DD + t] + ygp[(size_t)(b * 4 + 3) * DD + t]) /
             (sumC + 1e-8f);
  float nx = bsum(xg * xg);
  float ny = bsum(yg * yg);
  float dt = bsum(xg * yg);
  if (t == 0) {
    float mx = fmaxf(sqrtf(nx), 1e-12f);
    float my = fmaxf(sqrtf(ny), 1e-12f);
    float cosv = dt / (mx * my);
    float lb = (baryA[b] + baryB[b]) * (1.0f / ((float)NN * (float)DD));
    lossArr[b] = Lmain + 0.5f * lb + 0.2f * (1.0f - cosv);
  }
}

__global__ void final_mean(const float* __restrict__ lossArr, float* __restrict__ out) {
  int t = threadIdx.x;
  float v = (t < BB) ? lossArr[t] : 0.f;
  v = waveReduceSum(v);
  if (t == 0) out[0] = v * (1.0f / BB);
}

// ---------------- launch ----------------
extern "C" void kernel_launch(void* const* d_in, const int* in_sizes, int n_in,
                              void* d_out, int out_size, void* d_ws, size_t ws_size,
                              hipStream_t stream) {
  const float* X = (const float*)d_in[0];
  const float* Y = (const float*)d_in[1];
  float* out = (float*)d_out;
  char* ws = (char*)d_ws;
  size_t off = 0;
  auto take = [&](size_t bytes) -> char* {
    char* p = ws + off;
    off = (off + bytes + 255) & ~(size_t)255;
    return p;
  };
  _Float16* Xh = (_Float16*)take((size_t)BB * NN * DD * 2);
  _Float16* Yh = (_Float16*)take((size_t)BB * NN * DD * 2);
  _Float16* A2 = (_Float16*)take((size_t)BB * NN * NN * 2);
  _Float16* A2T = (_Float16*)take((size_t)BB * NN * NN * 2);
  size_t zstart = off;
  float* F = (float*)take((size_t)BB * NN * 4);
  float* G = (float*)take((size_t)BB * NN * 4);
  unsigned* bar = (unsigned*)take(16 * 64 * 4);
  float* baryA = (float*)take(64);
  float* baryB = (float*)take(64);
  size_t zlen = off - zstart;
  float* r = (float*)take((size_t)BB * NN * 4);
  float* c = (float*)take((size_t)BB * NN * 4);
  float* Lrow = (float*)take((size_t)BB * NN * 4);
  float* xgp = (float*)take((size_t)BB * 4 * DD * 4);
  float* ygp = (float*)take((size_t)BB * 4 * DD * 4);
  float* lossArr = (float*)take(64);
  (void)in_sizes; (void)n_in; (void)out_size; (void)ws_size;

  hipMemsetAsync(ws + zstart, 0, zlen, stream);

  normalize_kernel<<<dim3(2 * BB * NN / 4), dim3(256), 0, stream>>>(X, Y, Xh, Yh);
  gemm_a2_kernel<<<dim3(NN / 128, NN / 128, BB), dim3(256), 0, stream>>>(Xh, Yh, A2);
  gemm_a2_kernel<<<dim3(NN / 128, NN / 128, BB), dim3(256), 0, stream>>>(Yh, Xh, A2T);
  sinkhorn_kernel<<<dim3(256), dim3(512), 0, stream>>>(A2, A2T, F, G, r, c, Lrow, bar);
  bary_kernel<<<dim3(NN / 64, BB), dim3(512), 0, stream>>>(A2, F, G, r, Y, X, baryA);
  bary_kernel<<<dim3(NN / 64, BB), dim3(512), 0, stream>>>(A2T, G, F, c, X, Y, baryB);
  xg_kernel<<<dim3(4, BB), dim3(256), 0, stream>>>(X, Y, r, c, xgp, ygp);
  finalize_batch<<<dim3(BB), dim3(256), 0, stream>>>(r, c, Lrow, xgp, ygp, baryA, baryB, lossArr);
  final_mean<<<dim3(1), dim3(64), 0, stream>>>(lossArr, out);
}

// Round 4
// 2463.868 us; speedup vs baseline: 4.1483x; 1.1827x over previous
//
#include <hip/hip_runtime.h>
#include <hip/hip_fp16.h>

#define BB 16
#define NN 1024
#define DD 256

typedef _Float16 h8 __attribute__((ext_vector_type(8)));
typedef _Float16 hv4 __attribute__((ext_vector_type(4)));
typedef float f32x4 __attribute__((ext_vector_type(4)));

#if __has_builtin(__builtin_amdgcn_exp2f)
#define EXP2F(x) __builtin_amdgcn_exp2f(x)
#else
#define EXP2F(x) exp2f(x)
#endif
#if __has_builtin(__builtin_amdgcn_logf)
#define LOG2F(x) __builtin_amdgcn_logf(x)
#else
#define LOG2F(x) log2f(x)
#endif

// log2-domain: A2s = -100*log2e*relu(1-S) - CPOS2*|i-j|   (pos prior folded in, fp16)
constexpr float K_A2  = -144.26950408889634f;                 // -100*log2(e)
constexpr float CPOS2 = (float)(0.2 * 1.4426950408889634 / 1023.0);
constexpr float C1    = 0.06931471805599453f;                 // ln2/10 : C_content = -C1*A2content
constexpr float BASE2 = -10.0f;                               // log2(1/1024 + 1e-12)

__device__ __forceinline__ float waveReduceSum(float v) {
#pragma unroll
  for (int o = 32; o; o >>= 1) v += __shfl_xor(v, o);
  return v;
}

// Pinned 16-byte load: inline asm so the compiler CANNOT rematerialize (re-load)
// the value inside the sinkhorn loop. Waitcnt embedded -> result valid on return.
__device__ __forceinline__ h8 lda16(const _Float16* p) {
  f32x4 r;
  asm volatile("global_load_dwordx4 %0, %1, off\n\ts_waitcnt vmcnt(0)"
               : "=v"(r) : "v"(p) : "memory");
  return __builtin_bit_cast(h8, r);
}

// Coherent (L1/L2-bypassing) ops for cross-XCD f/g exchange: sc0 sc1 makes the
// store write-through to the coherent point and the load read from it. This
// replaces __threadfence()-driven L2 writeback/invalidate storms (73 MB/dispatch
// of WRITE_SIZE in round 3).
__device__ __forceinline__ void st_wt(float* p, float v) {
  asm volatile("global_store_dword %0, %1, off sc0 sc1" :: "v"(p), "v"(v) : "memory");
}
__device__ __forceinline__ f32x4 ld4_cv(const float* p) {
  f32x4 r;
  asm volatile("global_load_dwordx4 %0, %1, off sc0 sc1\n\ts_waitcnt vmcnt(0)"
               : "=v"(r) : "v"(p) : "memory");
  return r;
}
__device__ __forceinline__ float ld_cv(const float* p) {
  float r;
  asm volatile("global_load_dword %0, %1, off sc0 sc1\n\ts_waitcnt vmcnt(0)"
               : "=v"(r) : "v"(p) : "memory");
  return r;
}

// ---------------- K1: normalize rows of X and Y -> fp16 ----------------
__global__ __launch_bounds__(256) void normalize_kernel(
    const float* __restrict__ X, const float* __restrict__ Y,
    _Float16* __restrict__ Xh, _Float16* __restrict__ Yh) {
  int wave = threadIdx.x >> 6;
  int lane = threadIdx.x & 63;
  int row = blockIdx.x * 4 + wave;           // 0 .. 2*BB*NN-1
  const float* src;
  _Float16* dst;
  if (row < BB * NN) { src = X + (size_t)row * DD; dst = Xh + (size_t)row * DD; }
  else { int r2 = row - BB * NN; src = Y + (size_t)r2 * DD; dst = Yh + (size_t)r2 * DD; }
  float4 v = *(const float4*)(src + lane * 4);
  float ss = v.x * v.x + v.y * v.y + v.z * v.z + v.w * v.w;
  ss = waveReduceSum(ss);
  float sc = 1.0f / fmaxf(sqrtf(ss), 1e-12f);
  hv4 hv;
  hv[0] = (_Float16)(v.x * sc); hv[1] = (_Float16)(v.y * sc);
  hv[2] = (_Float16)(v.z * sc); hv[3] = (_Float16)(v.w * sc);
  *(hv4*)(dst + lane * 4) = hv;
}

// ---------------- K2: S = Ah . Bh^T per batch, write A2s (content+pos, fp16) ----
__global__ __launch_bounds__(256) void gemm_a2_kernel(
    const _Float16* __restrict__ Ah, const _Float16* __restrict__ Bh,
    _Float16* __restrict__ Out) {
  const int b = blockIdx.z;
  const int I0 = blockIdx.y * 128;
  const int J0 = blockIdx.x * 128;
  const int lane = threadIdx.x & 63;
  const int wave = threadIdx.x >> 6;
  const int m = lane & 15, quad = lane >> 4;
  const _Float16* Abase = Ah + ((size_t)b * NN + I0 + wave * 32) * DD;
  const _Float16* Bbase = Bh + ((size_t)b * NN + J0) * DD;
  f32x4 acc[2][8] = {};
  for (int k0 = 0; k0 < DD; k0 += 32) {
    int koff = k0 + quad * 8;
    h8 a0 = *(const h8*)(Abase + (size_t)m * DD + koff);
    h8 a1 = *(const h8*)(Abase + (size_t)(m + 16) * DD + koff);
#pragma unroll
    for (int t = 0; t < 8; ++t) {
      h8 bf = *(const h8*)(Bbase + (size_t)(t * 16 + m) * DD + koff);
      acc[0][t] = __builtin_amdgcn_mfma_f32_16x16x32_f16(a0, bf, acc[0][t], 0, 0, 0);
      acc[1][t] = __builtin_amdgcn_mfma_f32_16x16x32_f16(a1, bf, acc[1][t], 0, 0, 0);
    }
  }
  _Float16* Ob = Out + ((size_t)b * NN + I0 + wave * 32) * NN + J0;
#pragma unroll
  for (int a = 0; a < 2; ++a)
#pragma unroll
    for (int t = 0; t < 8; ++t)
#pragma unroll
      for (int r = 0; r < 4; ++r) {
        int row = a * 16 + quad * 4 + r;
        int col = t * 16 + m;
        float s = acc[a][t][r];
        float ri = (float)(I0 + wave * 32 + row);
        float ci = (float)(J0 + col);
        Ob[(size_t)row * NN + col] =
            (_Float16)(K_A2 * fmaxf(1.0f - s, 0.0f) - CPOS2 * fabsf(ri - ci));
      }
}

// ---------------- Sinkhorn persistent kernel (asm-pinned rows in registers) -------
// Barrier: ALL RELAXED atomics (no compiler cache-maintenance). Ordering comes
// from write-through stores + vmcnt drain. 16 arrivals/batch; last arriver
// stores epoch flag on a separate cacheline; others poll read-only + s_sleep.
__device__ __forceinline__ void group_barrier(unsigned* ctr, unsigned* flag,
                                              unsigned epoch) {
  __syncthreads();   // compiler drains vmcnt before s_barrier -> f/g stores acked
  if (threadIdx.x == 0) {
    asm volatile("s_waitcnt vmcnt(0)" ::: "memory");
    unsigned old = __hip_atomic_fetch_add(ctr, 1u, __ATOMIC_RELAXED,
                                          __HIP_MEMORY_SCOPE_AGENT);
    if (old == 16u * epoch - 1u) {
      __hip_atomic_store(flag, epoch, __ATOMIC_RELAXED, __HIP_MEMORY_SCOPE_AGENT);
    } else {
      while (__hip_atomic_load(flag, __ATOMIC_RELAXED, __HIP_MEMORY_SCOPE_AGENT) <
             epoch) {
        __builtin_amdgcn_s_sleep(2);
      }
    }
  }
  __syncthreads();
}

// 16 floats of the dual vector via coherent loads (bypass possibly-stale caches)
__device__ __forceinline__ void loadVec16(const float* __restrict__ v, int j0,
                                          float (&out)[16]) {
  f32x4 g0 = ld4_cv(v + j0);
  f32x4 g1 = ld4_cv(v + j0 + 4);
  f32x4 g2 = ld4_cv(v + 512 + j0);
  f32x4 g3 = ld4_cv(v + 512 + j0 + 4);
  out[0] = g0[0]; out[1] = g0[1]; out[2] = g0[2]; out[3] = g0[3];
  out[4] = g1[0]; out[5] = g1[1]; out[6] = g1[2]; out[7] = g1[3];
  out[8] = g2[0]; out[9] = g2[1]; out[10] = g2[2]; out[11] = g2[3];
  out[12] = g3[0]; out[13] = g3[1]; out[14] = g3[2]; out[15] = g3[3];
}

__device__ __forceinline__ float lseRow(const h8 (&rw)[2], const float (&gv)[16]) {
  float x[16];
#pragma unroll
  for (int k = 0; k < 8; ++k) {
    x[k]     = (float)rw[0][k] + gv[k];
    x[8 + k] = (float)rw[1][k] + gv[8 + k];
  }
  float m = x[0];
#pragma unroll
  for (int k = 1; k < 16; ++k) m = fmaxf(m, x[k]);
#pragma unroll
  for (int o = 32; o; o >>= 1) m = fmaxf(m, __shfl_xor(m, o));
  float s = 0.f;
#pragma unroll
  for (int k = 0; k < 16; ++k) s += EXP2F(x[k] - m);
  s = waveReduceSum(s);
  return BASE2 - (m + LOG2F(s));
}

// grid 256 blocks x 512 thr: batch = bid&15, 16 blocks/batch (1 block/CU,
// guaranteed co-resident). Each wave owns 8 rows of A2 and 8 rows of A2T,
// pinned in VGPRs via inline-asm loads (128 VGPRs of data).
__global__ __launch_bounds__(512, 2) void sinkhorn_kernel(
    const _Float16* __restrict__ A2, const _Float16* __restrict__ A2T,
    float* __restrict__ F, float* __restrict__ G,
    float* __restrict__ rOut, float* __restrict__ cOut,
    float* __restrict__ LrowOut, unsigned* __restrict__ bar) {
  const int batch = blockIdx.x & 15;
  const int blkSub = blockIdx.x >> 4;            // 0..15
  const int lane = threadIdx.x & 63;
  const int wave = threadIdx.x >> 6;             // 0..7
  const int r0 = blkSub * 64 + wave * 8;         // 8 rows per wave
  const int j0 = lane * 8;
  const _Float16* Pa = A2 + (size_t)batch * NN * NN;
  const _Float16* Pt = A2T + (size_t)batch * NN * NN;
  float* Fb = F + batch * NN;
  float* Gb = G + batch * NN;
  unsigned* ctr = bar + batch * 64;              // 256B stride per batch
  unsigned* flg = ctr + 32;                      // separate cacheline

  h8 ra[8][2], rt[8][2];
#pragma unroll
  for (int r = 0; r < 8; ++r) {
    const _Float16* rowA = Pa + (size_t)(r0 + r) * NN + j0;
    const _Float16* rowT = Pt + (size_t)(r0 + r) * NN + j0;
    ra[r][0] = lda16(rowA);
    ra[r][1] = lda16(rowA + 512);
    rt[r][0] = lda16(rowT);
    rt[r][1] = lda16(rowT + 512);
  }
  unsigned ep = 0;
  for (int it = 0; it < 50; ++it) {
    {
      float gv[16];
      loadVec16(Gb, j0, gv);
#pragma unroll
      for (int r = 0; r < 8; ++r) {
        float res = lseRow(ra[r], gv);
        if (lane == 0) st_wt(Fb + r0 + r, res);
      }
    }
    ++ep; group_barrier(ctr, flg, ep);
    {
      float fv[16];
      loadVec16(Fb, j0, fv);
#pragma unroll
      for (int r = 0; r < 8; ++r) {
        float res = lseRow(rt[r], fv);
        if (lane == 0) st_wt(Gb + r0 + r, res);
      }
    }
    ++ep; group_barrier(ctr, flg, ep);
  }
  // Epilogue: r_i = sum_j T, c_j = sum_i T, Lrow_i = sum_j T*C_content
  float fv[16], gv[16];
  loadVec16(Fb, j0, fv);
  loadVec16(Gb, j0, gv);
#pragma unroll
  for (int r = 0; r < 8; ++r) {
    int i = r0 + r;
    float fi = ld_cv(Fb + i);
    float gi = ld_cv(Gb + i);
    float fr = (float)i;
    float sr = 0.f, sl = 0.f, sc = 0.f;
#pragma unroll
    for (int k = 0; k < 8; ++k) {
      float a2a = (float)ra[r][0][k];
      float a2b = (float)ra[r][1][k];
      float Ta = EXP2F(a2a + fi + gv[k]);
      float Tb = EXP2F(a2b + fi + gv[8 + k]);
      sr += Ta + Tb;
      float ca = a2a + CPOS2 * fabsf(fr - (float)(j0 + k));
      float cb = a2b + CPOS2 * fabsf(fr - (float)(512 + j0 + k));
      sl = fmaf(Ta, ca, sl);
      sl = fmaf(Tb, cb, sl);
      sc += EXP2F((float)rt[r][0][k] + gi + fv[k]);
      sc += EXP2F((float)rt[r][1][k] + gi + fv[8 + k]);
    }
    sr = waveReduceSum(sr);
    sl = waveReduceSum(sl);
    sc = waveReduceSum(sc);
    if (lane == 0) {
      rOut[batch * NN + i] = sr;
      cOut[batch * NN + i] = sc;
      LrowOut[batch * NN + i] = -C1 * sl;
    }
  }
}

// ---------------- K6: num = T @ Emb ; accumulate sum((Ref - num/denom)^2) ----------
__global__ __launch_bounds__(512) void bary_kernel(
    const _Float16* __restrict__ P, const float* __restrict__ rowv,
    const float* __restrict__ colv, const float* __restrict__ denom,
    const float* __restrict__ Emb, const float* __restrict__ Ref,
    float* __restrict__ baryAcc) {
  const int b = blockIdx.y;
  const int I0 = blockIdx.x * 64;
  const _Float16* Pb = P + (size_t)b * NN * NN;
  const float* rv = rowv + b * NN;
  const float* cvv = colv + b * NN;
  const float* dn = denom + b * NN;
  const float* Eb = Emb + (size_t)b * NN * DD;
  const float* Rb = Ref + (size_t)b * NN * DD;
  __shared__ float Tl[64 * 64];
  __shared__ float red[8];
  const int t = threadIdx.x;
  const int rg = t >> 8, d = t & 255;
  float acc[32];
#pragma unroll
  for (int k = 0; k < 32; ++k) acc[k] = 0.f;
  for (int ch = 0; ch < 16; ++ch) {
    __syncthreads();
    {
      int jj = t & 63;
      int jabs = ch * 64 + jj;
      float gvv = cvv[jabs];
      int ii0 = (t >> 6) * 8;
#pragma unroll
      for (int k = 0; k < 8; ++k) {
        int ii = ii0 + k;
        int iabs = I0 + ii;
        float a2f = (float)Pb[(size_t)iabs * NN + jabs];
        Tl[ii * 64 + jj] = EXP2F(a2f + rv[iabs] + gvv);
      }
    }
    __syncthreads();
    const float* Yc = Eb + (size_t)(ch * 64) * DD + d;
    for (int jg = 0; jg < 16; ++jg) {
      float y0 = Yc[(size_t)(jg * 4 + 0) * DD];
      float y1 = Yc[(size_t)(jg * 4 + 1) * DD];
      float y2 = Yc[(size_t)(jg * 4 + 2) * DD];
      float y3 = Yc[(size_t)(jg * 4 + 3) * DD];
#pragma unroll
      for (int ii = 0; ii < 32; ++ii) {
        const float4 tv = *(const float4*)&Tl[(rg * 32 + ii) * 64 + jg * 4];
        acc[ii] = fmaf(tv.x, y0, acc[ii]);
        acc[ii] = fmaf(tv.y, y1, acc[ii]);
        acc[ii] = fmaf(tv.z, y2, acc[ii]);
        acc[ii] = fmaf(tv.w, y3, acc[ii]);
      }
    }
  }
  float vs = 0.f;
#pragma unroll
  for (int ii = 0; ii < 32; ++ii) {
    int iabs = I0 + rg * 32 + ii;
    float val = Rb[(size_t)iabs * DD + d] - acc[ii] / (dn[iabs] + 1e-8f);
    vs = fmaf(val, val, vs);
  }
  vs = waveReduceSum(vs);
  int lane = t & 63, wave = t >> 6;
  if (lane == 0) red[wave] = vs;
  __syncthreads();
  if (t == 0) {
    float tot = 0.f;
    for (int w = 0; w < 8; ++w) tot += red[w];
    atomicAdd(baryAcc + b, tot);
  }
}

// ---------------- K7: partial global sums X*r, Y*c ----------------
__global__ __launch_bounds__(256) void xg_kernel(
    const float* __restrict__ X, const float* __restrict__ Y,
    const float* __restrict__ r, const float* __restrict__ c,
    float* __restrict__ xgp, float* __restrict__ ygp) {
  const int b = blockIdx.y, seg = blockIdx.x, d = threadIdx.x;
  float ax = 0.f, ay = 0.f;
  for (int ii = 0; ii < 256; ++ii) {
    int i = seg * 256 + ii;
    float rvv = r[b * NN + i];
    float cvv = c[b * NN + i];
    ax = fmaf(X[((size_t)b * NN + i) * DD + d], rvv, ax);
    ay = fmaf(Y[((size_t)b * NN + i) * DD + d], cvv, ay);
  }
  xgp[(size_t)(b * 4 + seg) * DD + d] = ax;
  ygp[(size_t)(b * 4 + seg) * DD + d] = ay;
}

// ---------------- K8: per-batch finalize ----------------
__global__ __launch_bounds__(256) void finalize_batch(
    const float* __restrict__ r, const float* __restrict__ c,
    const float* __restrict__ Lrow, const float* __restrict__ xgp,
    const float* __restrict__ ygp, const float* __restrict__ baryA,
    const float* __restrict__ baryB, float* __restrict__ lossArr) {
  const int b = blockIdx.x;
  const int t = threadIdx.x;
  __shared__ float sd[256];
  auto bsum = [&](float v) -> float {
    sd[t] = v; __syncthreads();
    for (int o = 128; o; o >>= 1) { if (t < o) sd[t] += sd[t + o]; __syncthreads(); }
    float res = sd[0]; __syncthreads();
    return res;
  };
  float vr = 0.f, vc = 0.f, vl = 0.f;
  for (int k = 0; k < 4; ++k) {
    int i = t + 256 * k;
    vr += r[b * NN + i];
    vc += c[b * NN + i];
    vl += Lrow[b * NN + i];
  }
  float sumR = bsum(vr);
  float sumC = bsum(vc);
  float Lmain = bsum(vl);
  float xg = (xgp[(size_t)(b * 4 + 0) * DD + t] + xgp[(size_t)(b * 4 + 1) * DD + t] +
              xgp[(size_t)(b * 4 + 2) * DD + t] + xgp[(size_t)(b * 4 + 3) * DD + t]) /
             (sumR + 1e-8f);
  float yg = (ygp[(size_t)(b * 4 + 0) * DD + t] + ygp[(size_t)(b * 4 + 1) * DD + t] +
              ygp[(size_t)(b * 4 + 2) * DD + t] + ygp[(size_t)(b * 4 + 3) * DD + t]) /
             (sumC + 1e-8f);
  float nx = bsum(xg * xg);
  float ny = bsum(yg * yg);
  float dt = bsum(xg * yg);
  if (t == 0) {
    float mx = fmaxf(sqrtf(nx), 1e-12f);
    float my = fmaxf(sqrtf(ny), 1e-12f);
    float cosv = dt / (mx * my);
    float lb = (baryA[b] + baryB[b]) * (1.0f / ((float)NN * (float)DD));
    lossArr[b] = Lmain + 0.5f * lb + 0.2f * (1.0f - cosv);
  }
}

__global__ void final_mean(const float* __restrict__ lossArr, float* __restrict__ out) {
  int t = threadIdx.x;
  float v = (t < BB) ? lossArr[t] : 0.f;
  v = waveReduceSum(v);
  if (t == 0) out[0] = v * (1.0f / BB);
}

// ---------------- launch ----------------
extern "C" void kernel_launch(void* const* d_in, const int* in_sizes, int n_in,
                              void* d_out, int out_size, void* d_ws, size_t ws_size,
                              hipStream_t stream) {
  const float* X = (const float*)d_in[0];
  const float* Y = (const float*)d_in[1];
  float* out = (float*)d_out;
  char* ws = (char*)d_ws;
  size_t off = 0;
  auto take = [&](size_t bytes) -> char* {
    char* p = ws + off;
    off = (off + bytes + 255) & ~(size_t)255;
    return p;
  };
  _Float16* Xh = (_Float16*)take((size_t)BB * NN * DD * 2);
  _Float16* Yh = (_Float16*)take((size_t)BB * NN * DD * 2);
  _Float16* A2 = (_Float16*)take((size_t)BB * NN * NN * 2);
  _Float16* A2T = (_Float16*)take((size_t)BB * NN * NN * 2);
  size_t zstart = off;
  float* F = (float*)take((size_t)BB * NN * 4);
  float* G = (float*)take((size_t)BB * NN * 4);
  unsigned* bar = (unsigned*)take(16 * 64 * 4);
  float* baryA = (float*)take(64);
  float* baryB = (float*)take(64);
  size_t zlen = off - zstart;
  float* r = (float*)take((size_t)BB * NN * 4);
  float* c = (float*)take((size_t)BB * NN * 4);
  float* Lrow = (float*)take((size_t)BB * NN * 4);
  float* xgp = (float*)take((size_t)BB * 4 * DD * 4);
  float* ygp = (float*)take((size_t)BB * 4 * DD * 4);
  float* lossArr = (float*)take(64);
  (void)in_sizes; (void)n_in; (void)out_size; (void)ws_size;

  hipMemsetAsync(ws + zstart, 0, zlen, stream);

  normalize_kernel<<<dim3(2 * BB * NN / 4), dim3(256), 0, stream>>>(X, Y, Xh, Yh);
  gemm_a2_kernel<<<dim3(NN / 128, NN / 128, BB), dim3(256), 0, stream>>>(Xh, Yh, A2);
  gemm_a2_kernel<<<dim3(NN / 128, NN / 128, BB), dim3(256), 0, stream>>>(Yh, Xh, A2T);
  sinkhorn_kernel<<<dim3(256), dim3(512), 0, stream>>>(A2, A2T, F, G, r, c, Lrow, bar);
  bary_kernel<<<dim3(NN / 64, BB), dim3(512), 0, stream>>>(A2, F, G, r, Y, X, baryA);
  bary_kernel<<<dim3(NN / 64, BB), dim3(512), 0, stream>>>(A2T, G, F, c, X, Y, baryB);
  xg_kernel<<<dim3(4, BB), dim3(256), 0, stream>>>(X, Y, r, c, xgp, ygp);
  finalize_batch<<<dim3(BB), dim3(256), 0, stream>>>(r, c, Lrow, xgp, ygp, baryA, baryB, lossArr);
  final_mean<<<dim3(1), dim3(64), 0, stream>>>(lossArr, out);
}

// Round 5
// 2297.539 us; speedup vs baseline: 4.4486x; 1.0724x over previous
//
#include <hip/hip_runtime.h>
#include <hip/hip_fp16.h>

#define BB 16
#define NN 1024
#define DD 256

typedef _Float16 h8 __attribute__((ext_vector_type(8)));
typedef _Float16 hv4 __attribute__((ext_vector_type(4)));
typedef float f32x4 __attribute__((ext_vector_type(4)));
typedef float f32x2 __attribute__((ext_vector_type(2)));

#if __has_builtin(__builtin_amdgcn_exp2f)
#define EXP2F(x) __builtin_amdgcn_exp2f(x)
#else
#define EXP2F(x) exp2f(x)
#endif
#if __has_builtin(__builtin_amdgcn_logf)
#define LOG2F(x) __builtin_amdgcn_logf(x)
#else
#define LOG2F(x) log2f(x)
#endif

// log2-domain: A2s = -100*log2e*relu(1-S) - CPOS2*|i-j|   (pos prior folded in, fp16)
constexpr float K_A2  = -144.26950408889634f;                 // -100*log2(e)
constexpr float CPOS2 = (float)(0.2 * 1.4426950408889634 / 1023.0);
constexpr float C1    = 0.06931471805599453f;                 // ln2/10 : C_content = -C1*A2content
constexpr float BASE2 = -10.0f;                               // log2(1/1024 + 1e-12)

__device__ __forceinline__ float waveReduceSum(float v) {
#pragma unroll
  for (int o = 32; o; o >>= 1) v += __shfl_xor(v, o);
  return v;
}

// Pinned 16-byte load: inline asm so the compiler CANNOT rematerialize (re-load)
// the value inside the sinkhorn loop. Waitcnt embedded -> result valid on return.
__device__ __forceinline__ h8 lda16(const _Float16* p) {
  f32x4 r;
  asm volatile("global_load_dwordx4 %0, %1, off\n\ts_waitcnt vmcnt(0)"
               : "=v"(r) : "v"(p) : "memory");
  return __builtin_bit_cast(h8, r);
}

// Coherent (cache-bypassing) ops for cross-XCD f/g exchange.
__device__ __forceinline__ void st_wt4(float* p, float a, float b, float c, float d) {
  f32x4 v = {a, b, c, d};
  asm volatile("global_store_dwordx4 %0, %1, off sc0 sc1" :: "v"(p), "v"(v) : "memory");
}
__device__ __forceinline__ f32x2 ld2_cv(const float* p) {
  f32x2 r;
  asm volatile("global_load_dwordx2 %0, %1, off sc0 sc1\n\ts_waitcnt vmcnt(0)"
               : "=v"(r) : "v"(p) : "memory");
  return r;
}

// ---------------- K1: normalize rows of X and Y -> fp16 ----------------
__global__ __launch_bounds__(256) void normalize_kernel(
    const float* __restrict__ X, const float* __restrict__ Y,
    _Float16* __restrict__ Xh, _Float16* __restrict__ Yh) {
  int wave = threadIdx.x >> 6;
  int lane = threadIdx.x & 63;
  int row = blockIdx.x * 4 + wave;           // 0 .. 2*BB*NN-1
  const float* src;
  _Float16* dst;
  if (row < BB * NN) { src = X + (size_t)row * DD; dst = Xh + (size_t)row * DD; }
  else { int r2 = row - BB * NN; src = Y + (size_t)r2 * DD; dst = Yh + (size_t)r2 * DD; }
  float4 v = *(const float4*)(src + lane * 4);
  float ss = v.x * v.x + v.y * v.y + v.z * v.z + v.w * v.w;
  ss = waveReduceSum(ss);
  float sc = 1.0f / fmaxf(sqrtf(ss), 1e-12f);
  hv4 hv;
  hv[0] = (_Float16)(v.x * sc); hv[1] = (_Float16)(v.y * sc);
  hv[2] = (_Float16)(v.z * sc); hv[3] = (_Float16)(v.w * sc);
  *(hv4*)(dst + lane * 4) = hv;
}

// ---------------- K2: S = Ah . Bh^T per batch, write A2s (content+pos, fp16) ----
__global__ __launch_bounds__(256) void gemm_a2_kernel(
    const _Float16* __restrict__ Ah, const _Float16* __restrict__ Bh,
    _Float16* __restrict__ Out) {
  const int b = blockIdx.z;
  const int I0 = blockIdx.y * 128;
  const int J0 = blockIdx.x * 128;
  const int lane = threadIdx.x & 63;
  const int wave = threadIdx.x >> 6;
  const int m = lane & 15, quad = lane >> 4;
  const _Float16* Abase = Ah + ((size_t)b * NN + I0 + wave * 32) * DD;
  const _Float16* Bbase = Bh + ((size_t)b * NN + J0) * DD;
  f32x4 acc[2][8] = {};
  for (int k0 = 0; k0 < DD; k0 += 32) {
    int koff = k0 + quad * 8;
    h8 a0 = *(const h8*)(Abase + (size_t)m * DD + koff);
    h8 a1 = *(const h8*)(Abase + (size_t)(m + 16) * DD + koff);
#pragma unroll
    for (int t = 0; t < 8; ++t) {
      h8 bf = *(const h8*)(Bbase + (size_t)(t * 16 + m) * DD + koff);
      acc[0][t] = __builtin_amdgcn_mfma_f32_16x16x32_f16(a0, bf, acc[0][t], 0, 0, 0);
      acc[1][t] = __builtin_amdgcn_mfma_f32_16x16x32_f16(a1, bf, acc[1][t], 0, 0, 0);
    }
  }
  _Float16* Ob = Out + ((size_t)b * NN + I0 + wave * 32) * NN + J0;
#pragma unroll
  for (int a = 0; a < 2; ++a)
#pragma unroll
    for (int t = 0; t < 8; ++t)
#pragma unroll
      for (int r = 0; r < 4; ++r) {
        int row = a * 16 + quad * 4 + r;
        int col = t * 16 + m;
        float s = acc[a][t][r];
        float ri = (float)(I0 + wave * 32 + row);
        float ci = (float)(J0 + col);
        Ob[(size_t)row * NN + col] =
            (_Float16)(K_A2 * fmaxf(1.0f - s, 0.0f) - CPOS2 * fabsf(ri - ci));
      }
}

// ---------------- Sinkhorn persistent kernel ----------------
// Rows pinned in VGPRs (asm loads). Duals exchanged through the coherent point
// with sc0 sc1, but staged into LDS ONCE per block per half-iteration (round 4's
// per-thread coherent loads caused 964 MB of redundant fetch traffic).
// Barrier: all-RELAXED atomics (no cache-maintenance), counter + epoch flag on
// separate cachelines, explicit per-wave vmcnt drain before arrival.
__device__ __forceinline__ void group_barrier(unsigned* ctr, unsigned* flag,
                                              unsigned epoch) {
  asm volatile("s_waitcnt vmcnt(0)" ::: "memory");  // per-wave: stores ack'd
  __syncthreads();
  if (threadIdx.x == 0) {
    unsigned old = __hip_atomic_fetch_add(ctr, 1u, __ATOMIC_RELAXED,
                                          __HIP_MEMORY_SCOPE_AGENT);
    if (old == 16u * epoch - 1u) {
      __hip_atomic_store(flag, epoch, __ATOMIC_RELAXED, __HIP_MEMORY_SCOPE_AGENT);
    } else {
      while (__hip_atomic_load(flag, __ATOMIC_RELAXED, __HIP_MEMORY_SCOPE_AGENT) <
             epoch) {
        __builtin_amdgcn_s_sleep(2);
      }
    }
  }
  __syncthreads();
}

// Cooperative stage: 512 threads load 2 consecutive floats each (coherent) -> LDS.
__device__ __forceinline__ void stageToLds(float* lds, const float* __restrict__ src,
                                           int t) {
  f32x2 v = ld2_cv(src + 2 * t);
  lds[2 * t] = v[0];
  lds[2 * t + 1] = v[1];
}

__device__ __forceinline__ void ldsVec16(const float* lds, int j0, float (&out)[16]) {
#pragma unroll
  for (int k = 0; k < 8; ++k) {
    out[k] = lds[j0 + k];
    out[8 + k] = lds[512 + j0 + k];
  }
}

__device__ __forceinline__ float lseRow(const h8 (&rw)[2], const float (&gv)[16]) {
  float x[16];
#pragma unroll
  for (int k = 0; k < 8; ++k) {
    x[k]     = (float)rw[0][k] + gv[k];
    x[8 + k] = (float)rw[1][k] + gv[8 + k];
  }
  float m = x[0];
#pragma unroll
  for (int k = 1; k < 16; ++k) m = fmaxf(m, x[k]);
#pragma unroll
  for (int o = 32; o; o >>= 1) m = fmaxf(m, __shfl_xor(m, o));
  float s = 0.f;
#pragma unroll
  for (int k = 0; k < 16; ++k) s += EXP2F(x[k] - m);
  s = waveReduceSum(s);
  return BASE2 - (m + LOG2F(s));
}

// grid 256 blocks x 512 thr: batch = bid&15, 16 blocks/batch (1 block/CU).
// Each wave owns 8 rows of A2 and 8 rows of A2T pinned in VGPRs.
__global__ __launch_bounds__(512, 2) void sinkhorn_kernel(
    const _Float16* __restrict__ A2, const _Float16* __restrict__ A2T,
    float* __restrict__ F, float* __restrict__ G,
    float* __restrict__ rOut, float* __restrict__ cOut,
    float* __restrict__ LrowOut, unsigned* __restrict__ bar) {
  __shared__ float ldsG[NN];   // staged g (phase 1 input); final G after loop
  __shared__ float ldsF[NN];   // staged f (phase 2 input); final F after loop
  const int batch = blockIdx.x & 15;
  const int blkSub = blockIdx.x >> 4;            // 0..15
  const int t = threadIdx.x;
  const int lane = t & 63;
  const int wave = t >> 6;                       // 0..7
  const int r0 = blkSub * 64 + wave * 8;         // 8 rows per wave
  const int j0 = lane * 8;
  const _Float16* Pa = A2 + (size_t)batch * NN * NN;
  const _Float16* Pt = A2T + (size_t)batch * NN * NN;
  float* Fb = F + batch * NN;
  float* Gb = G + batch * NN;
  unsigned* ctr = bar + batch * 64;              // 256B stride per batch
  unsigned* flg = ctr + 32;                      // separate cacheline

  h8 ra[8][2], rt[8][2];
#pragma unroll
  for (int r = 0; r < 8; ++r) {
    const _Float16* rowA = Pa + (size_t)(r0 + r) * NN + j0;
    const _Float16* rowT = Pt + (size_t)(r0 + r) * NN + j0;
    ra[r][0] = lda16(rowA);
    ra[r][1] = lda16(rowA + 512);
    rt[r][0] = lda16(rowT);
    rt[r][1] = lda16(rowT + 512);
  }
  // g0 = 0
  ldsG[t] = 0.f;
  ldsG[t + 512] = 0.f;
  __syncthreads();

  unsigned ep = 0;
  for (int it = 0; it < 50; ++it) {
    {  // phase 1: f from ra + g
      float gv[16];
      ldsVec16(ldsG, j0, gv);
      float rs[8];
#pragma unroll
      for (int r = 0; r < 8; ++r) rs[r] = lseRow(ra[r], gv);
      if (lane == 0) {
        st_wt4(Fb + r0, rs[0], rs[1], rs[2], rs[3]);
        st_wt4(Fb + r0 + 4, rs[4], rs[5], rs[6], rs[7]);
      }
    }
    ++ep; group_barrier(ctr, flg, ep);
    stageToLds(ldsF, Fb, t);
    __syncthreads();
    {  // phase 2: g from rt + f
      float fv[16];
      ldsVec16(ldsF, j0, fv);
      float rs[8];
#pragma unroll
      for (int r = 0; r < 8; ++r) rs[r] = lseRow(rt[r], fv);
      if (lane == 0) {
        st_wt4(Gb + r0, rs[0], rs[1], rs[2], rs[3]);
        st_wt4(Gb + r0 + 4, rs[4], rs[5], rs[6], rs[7]);
      }
    }
    ++ep; group_barrier(ctr, flg, ep);
    stageToLds(ldsG, Gb, t);
    __syncthreads();
  }
  // Epilogue. ldsF = final f, ldsG = final g.
  float fv[16], gv[16];
  ldsVec16(ldsF, j0, fv);
  ldsVec16(ldsG, j0, gv);
#pragma unroll
  for (int r = 0; r < 8; ++r) {
    int i = r0 + r;
    float fi = ldsF[i];
    float gi = ldsG[i];
    float fr = (float)i;
    float sr = 0.f, sl = 0.f, sc = 0.f;
#pragma unroll
    for (int k = 0; k < 8; ++k) {
      float a2a = (float)ra[r][0][k];
      float a2b = (float)ra[r][1][k];
      float Ta = EXP2F(a2a + fi + gv[k]);
      float Tb = EXP2F(a2b + fi + gv[8 + k]);
      sr += Ta + Tb;
      float ca = a2a + CPOS2 * fabsf(fr - (float)(j0 + k));
      float cb = a2b + CPOS2 * fabsf(fr - (float)(512 + j0 + k));
      sl = fmaf(Ta, ca, sl);
      sl = fmaf(Tb, cb, sl);
      sc += EXP2F((float)rt[r][0][k] + gi + fv[k]);
      sc += EXP2F((float)rt[r][1][k] + gi + fv[8 + k]);
    }
    sr = waveReduceSum(sr);
    sl = waveReduceSum(sl);
    sc = waveReduceSum(sc);
    if (lane == 0) {
      rOut[batch * NN + i] = sr;
      cOut[batch * NN + i] = sc;
      LrowOut[batch * NN + i] = -C1 * sl;
    }
  }
}

// ---------------- K6: num = T @ Emb ; accumulate sum((Ref - num/denom)^2) ----------
__global__ __launch_bounds__(512) void bary_kernel(
    const _Float16* __restrict__ P, const float* __restrict__ rowv,
    const float* __restrict__ colv, const float* __restrict__ denom,
    const float* __restrict__ Emb, const float* __restrict__ Ref,
    float* __restrict__ baryAcc) {
  const int b = blockIdx.y;
  const int I0 = blockIdx.x * 64;
  const _Float16* Pb = P + (size_t)b * NN * NN;
  const float* rv = rowv + b * NN;
  const float* cvv = colv + b * NN;
  const float* dn = denom + b * NN;
  const float* Eb = Emb + (size_t)b * NN * DD;
  const float* Rb = Ref + (size_t)b * NN * DD;
  __shared__ float Tl[64 * 64];
  __shared__ float red[8];
  const int t = threadIdx.x;
  const int rg = t >> 8, d = t & 255;
  float acc[32];
#pragma unroll
  for (int k = 0; k < 32; ++k) acc[k] = 0.f;
  for (int ch = 0; ch < 16; ++ch) {
    __syncthreads();
    {
      int jj = t & 63;
      int jabs = ch * 64 + jj;
      float gvv = cvv[jabs];
      int ii0 = (t >> 6) * 8;
#pragma unroll
      for (int k = 0; k < 8; ++k) {
        int ii = ii0 + k;
        int iabs = I0 + ii;
        float a2f = (float)Pb[(size_t)iabs * NN + jabs];
        Tl[ii * 64 + jj] = EXP2F(a2f + rv[iabs] + gvv);
      }
    }
    __syncthreads();
    const float* Yc = Eb + (size_t)(ch * 64) * DD + d;
    for (int jg = 0; jg < 16; ++jg) {
      float y0 = Yc[(size_t)(jg * 4 + 0) * DD];
      float y1 = Yc[(size_t)(jg * 4 + 1) * DD];
      float y2 = Yc[(size_t)(jg * 4 + 2) * DD];
      float y3 = Yc[(size_t)(jg * 4 + 3) * DD];
#pragma unroll
      for (int ii = 0; ii < 32; ++ii) {
        const float4 tv = *(const float4*)&Tl[(rg * 32 + ii) * 64 + jg * 4];
        acc[ii] = fmaf(tv.x, y0, acc[ii]);
        acc[ii] = fmaf(tv.y, y1, acc[ii]);
        acc[ii] = fmaf(tv.z, y2, acc[ii]);
        acc[ii] = fmaf(tv.w, y3, acc[ii]);
      }
    }
  }
  float vs = 0.f;
#pragma unroll
  for (int ii = 0; ii < 32; ++ii) {
    int iabs = I0 + rg * 32 + ii;
    float val = Rb[(size_t)iabs * DD + d] - acc[ii] / (dn[iabs] + 1e-8f);
    vs = fmaf(val, val, vs);
  }
  vs = waveReduceSum(vs);
  int lane = t & 63, wave = t >> 6;
  if (lane == 0) red[wave] = vs;
  __syncthreads();
  if (t == 0) {
    float tot = 0.f;
    for (int w = 0; w < 8; ++w) tot += red[w];
    atomicAdd(baryAcc + b, tot);
  }
}

// ---------------- K7: partial global sums X*r, Y*c ----------------
__global__ __launch_bounds__(256) void xg_kernel(
    const float* __restrict__ X, const float* __restrict__ Y,
    const float* __restrict__ r, const float* __restrict__ c,
    float* __restrict__ xgp, float* __restrict__ ygp) {
  const int b = blockIdx.y, seg = blockIdx.x, d = threadIdx.x;
  float ax = 0.f, ay = 0.f;
  for (int ii = 0; ii < 256; ++ii) {
    int i = seg * 256 + ii;
    float rvv = r[b * NN + i];
    float cvv = c[b * NN + i];
    ax = fmaf(X[((size_t)b * NN + i) * DD + d], rvv, ax);
    ay = fmaf(Y[((size_t)b * NN + i) * DD + d], cvv, ay);
  }
  xgp[(size_t)(b * 4 + seg) * DD + d] = ax;
  ygp[(size_t)(b * 4 + seg) * DD + d] = ay;
}

// ---------------- K8: per-batch finalize ----------------
__global__ __launch_bounds__(256) void finalize_batch(
    const float* __restrict__ r, const float* __restrict__ c,
    const float* __restrict__ Lrow, const float* __restrict__ xgp,
    const float* __restrict__ ygp, const float* __restrict__ baryA,
    const float* __restrict__ baryB, float* __restrict__ lossArr) {
  const int b = blockIdx.x;
  const int t = threadIdx.x;
  __shared__ float sd[256];
  auto bsum = [&](float v) -> float {
    sd[t] = v; __syncthreads();
    for (int o = 128; o; o >>= 1) { if (t < o) sd[t] += sd[t + o]; __syncthreads(); }
    float res = sd[0]; __syncthreads();
    return res;
  };
  float vr = 0.f, vc = 0.f, vl = 0.f;
  for (int k = 0; k < 4; ++k) {
    int i = t + 256 * k;
    vr += r[b * NN + i];
    vc += c[b * NN + i];
    vl += Lrow[b * NN + i];
  }
  float sumR = bsum(vr);
  float sumC = bsum(vc);
  float Lmain = bsum(vl);
  float xg = (xgp[(size_t)(b * 4 + 0) * DD + t] + xgp[(size_t)(b * 4 + 1) * DD + t] +
              xgp[(size_t)(b * 4 + 2) * DD + t] + xgp[(size_t)(b * 4 + 3) * DD + t]) /
             (sumR + 1e-8f);
  float yg = (ygp[(size_t)(b * 4 + 0) * DD + t] + ygp[(size_t)(b * 4 + 1) * DD + t] +
              ygp[(size_t)(b * 4 + 2) * DD + t] + ygp[(size_t)(b * 4 + 3) * DD + t]) /
             (sumC + 1e-8f);
  float nx = bsum(xg * xg);
  float ny = bsum(yg * yg);
  float dt = bsum(xg * yg);
  if (t == 0) {
    float mx = fmaxf(sqrtf(nx), 1e-12f);
    float my = fmaxf(sqrtf(ny), 1e-12f);
    float cosv = dt / (mx * my);
    float lb = (baryA[b] + baryB[b]) * (1.0f / ((float)NN * (float)DD));
    lossArr[b] = Lmain + 0.5f * lb + 0.2f * (1.0f - cosv);
  }
}

__global__ void final_mean(const float* __restrict__ lossArr, float* __restrict__ out) {
  int t = threadIdx.x;
  float v = (t < BB) ? lossArr[t] : 0.f;
  v = waveReduceSum(v);
  if (t == 0) out[0] = v * (1.0f / BB);
}

// ---------------- launch ----------------
extern "C" void kernel_launch(void* const* d_in, const int* in_sizes, int n_in,
                              void* d_out, int out_size, void* d_ws, size_t ws_size,
                              hipStream_t stream) {
  const float* X = (const float*)d_in[0];
  const float* Y = (const float*)d_in[1];
  float* out = (float*)d_out;
  char* ws = (char*)d_ws;
  size_t off = 0;
  auto take = [&](size_t bytes) -> char* {
    char* p = ws + off;
    off = (off + bytes + 255) & ~(size_t)255;
    return p;
  };
  _Float16* Xh = (_Float16*)take((size_t)BB * NN * DD * 2);
  _Float16* Yh = (_Float16*)take((size_t)BB * NN * DD * 2);
  _Float16* A2 = (_Float16*)take((size_t)BB * NN * NN * 2);
  _Float16* A2T = (_Float16*)take((size_t)BB * NN * NN * 2);
  size_t zstart = off;
  float* F = (float*)take((size_t)BB * NN * 4);
  float* G = (float*)take((size_t)BB * NN * 4);
  unsigned* bar = (unsigned*)take(16 * 64 * 4);
  float* baryA = (float*)take(64);
  float* baryB = (float*)take(64);
  size_t zlen = off - zstart;
  float* r = (float*)take((size_t)BB * NN * 4);
  float* c = (float*)take((size_t)BB * NN * 4);
  float* Lrow = (float*)take((size_t)BB * NN * 4);
  float* xgp = (float*)take((size_t)BB * 4 * DD * 4);
  float* ygp = (float*)take((size_t)BB * 4 * DD * 4);
  float* lossArr = (float*)take(64);
  (void)in_sizes; (void)n_in; (void)out_size; (void)ws_size;

  hipMemsetAsync(ws + zstart, 0, zlen, stream);

  normalize_kernel<<<dim3(2 * BB * NN / 4), dim3(256), 0, stream>>>(X, Y, Xh, Yh);
  gemm_a2_kernel<<<dim3(NN / 128, NN / 128, BB), dim3(256), 0, stream>>>(Xh, Yh, A2);
  gemm_a2_kernel<<<dim3(NN / 128, NN / 128, BB), dim3(256), 0, stream>>>(Yh, Xh, A2T);
  sinkhorn_kernel<<<dim3(256), dim3(512), 0, stream>>>(A2, A2T, F, G, r, c, Lrow, bar);
  bary_kernel<<<dim3(NN / 64, BB), dim3(512), 0, stream>>>(A2, F, G, r, Y, X, baryA);
  bary_kernel<<<dim3(NN / 64, BB), dim3(512), 0, stream>>>(A2T, G, F, c, X, Y, baryB);
  xg_kernel<<<dim3(4, BB), dim3(256), 0, stream>>>(X, Y, r, c, xgp, ygp);
  finalize_batch<<<dim3(BB), dim3(256), 0, stream>>>(r, c, Lrow, xgp, ygp, baryA, baryB, lossArr);
  final_mean<<<dim3(1), dim3(64), 0, stream>>>(lossArr, out);
}